// Round 4
// baseline (124.999 us; speedup 1.0000x reference)
//
#include <hip/hip_runtime.h>
#include <hip/hip_bf16.h>
#include <math.h>

// Problem constants
constexpr int Bb = 32;
constexpr int Ll = 1024;
constexpr int DC = 1024;
constexpr int DQ = 1024;
constexpr int Hh = 512;
#define NEG_NUM -10000.0f

typedef __attribute__((ext_vector_type(8))) short bf16x8;
typedef __attribute__((ext_vector_type(4))) float f32x4;

#define GLOAD_LDS16(g, l)                                                  \
    __builtin_amdgcn_global_load_lds(                                      \
        (const __attribute__((address_space(1))) void*)(g),                \
        (__attribute__((address_space(3))) void*)(l), 16, 0, 0)

__device__ inline unsigned short f2bf(float f) {           // RNE f32->bf16
    unsigned int x = __float_as_uint(f);
    unsigned int r = (x + 0x7FFFu + ((x >> 16) & 1u)) >> 16;
    return (unsigned short)r;
}

// ---------------------------------------------------------------------------
// prep, 2432 blocks:
//   [0,2048):    W1[:DC] (1024x512) -> w1t bf16 (512x1024 transposed)
//   [2048,2176): zero out_ctx (32768 floats)
//   [2176,2432): qb[b,h] = query[b,:] @ W1[DC:,h] + b1[h]
// ---------------------------------------------------------------------------
__global__ __launch_bounds__(256) void prep_kernel(const float* __restrict__ W1,
                                                   const float* __restrict__ query,
                                                   const float* __restrict__ b1,
                                                   unsigned short* __restrict__ w1t,
                                                   float* __restrict__ qb,
                                                   float* __restrict__ out_ctx) {
    __shared__ float red[4][64];
    const int bid = blockIdx.x;
    if (bid < 2048) {
        int idx = bid * 256 + threadIdx.x;   // n*1024 + k
        int n = idx >> 10, k = idx & 1023;
        w1t[idx] = f2bf(W1[(size_t)k * Hh + n]);
    } else if (bid < 2176) {
        out_ctx[(bid - 2048) * 256 + threadIdx.x] = 0.f;
    } else {
        const int qbid = bid - 2176;          // 0..255
        const int b  = qbid >> 3;
        const int hg = qbid & 7;
        const int hl = threadIdx.x & 63;
        const int j  = threadIdx.x >> 6;
        const int h  = hg * 64 + hl;
        const float* q = query + (size_t)b * DQ + j * 256;
        const float* w = W1 + (size_t)(DC + j * 256) * Hh + h;
        float a0 = 0.f, a1 = 0.f, a2 = 0.f, a3 = 0.f;
#pragma unroll 4
        for (int c = 0; c < 256; c += 4) {
            a0 += q[c + 0] * w[(size_t)(c + 0) * Hh];
            a1 += q[c + 1] * w[(size_t)(c + 1) * Hh];
            a2 += q[c + 2] * w[(size_t)(c + 2) * Hh];
            a3 += q[c + 3] * w[(size_t)(c + 3) * Hh];
        }
        red[j][hl] = (a0 + a1) + (a2 + a3);
        __syncthreads();
        if (j == 0)
            qb[(size_t)b * Hh + h] = red[0][hl] + red[1][hl] + red[2][hl] + red[3][hl] + b1[h];
    }
}

// ---------------------------------------------------------------------------
// Fused cvt + MFMA GEMM + tanh + w2 reduction.
//   BM=64, BN=512 (= all of H), BK=32, 256 thr / 4 waves; wave w owns cols
//   [w*128,(w+1)*128). ctx read ONCE from HBM as fp32, cvt'd in-reg, staged
//   to LDS bf16; w1t staged via global_load_lds. Double-buffered LDS,
//   one barrier per K-step (T3-minimum schedule). score written directly
//   (block owns its 64 rows exclusively) — no atomics, no zero-init.
// ---------------------------------------------------------------------------
__global__ __launch_bounds__(256, 2) void gemm_fused(const float* __restrict__ ctx,
                                                     const unsigned short* __restrict__ w1t,
                                                     const float* __restrict__ qb,
                                                     const float* __restrict__ w2,
                                                     float* __restrict__ score) {
    __shared__ unsigned short As[2][64 * 32];    // 2 x 4 KB, [m][k] 64B rows
    __shared__ unsigned short Bs[2][512 * 32];   // 2 x 32 KB, [n][k] 64B rows
    __shared__ float red[4][64];

    const int m0 = blockIdx.x * 64;
    const int tid = threadIdx.x;
    const int w = tid >> 6, lane = tid & 63;
    const int lr = lane & 15, lk = lane >> 4;
    const int arow = tid >> 2, akq = tid & 3;          // A staging: 4 thr/row
    const int brow = lane >> 2, bcolb = (lane & 3) * 16;  // B staging within chunk

    char* AsB = (char*)As;
    char* BsB = (char*)Bs;
    const char* w1tB = (const char*)w1t;

    f32x4 acc[4][8];
#pragma unroll
    for (int mf = 0; mf < 4; ++mf)
#pragma unroll
        for (int nf = 0; nf < 8; ++nf) acc[mf][nf] = (f32x4){0.f, 0.f, 0.f, 0.f};

    // ---- prologue: stage k0 = 0 into buffer 0 ----
#pragma unroll
    for (int i = 0; i < 8; ++i) {
        int chunk = w * 8 + i;                         // 32 chunks x 1 KB = Bs tile
        GLOAD_LDS16(w1tB + (size_t)(chunk * 16 + brow) * 2048 + bcolb,
                    BsB + chunk * 1024);
    }
    {
        const float* ag = ctx + (size_t)(m0 + arow) * DC + akq * 8;
        float4 r0 = *(const float4*)ag, r1 = *(const float4*)(ag + 4);
        union { unsigned short us[8]; bf16x8 v; } pk;
        pk.us[0] = f2bf(r0.x); pk.us[1] = f2bf(r0.y); pk.us[2] = f2bf(r0.z); pk.us[3] = f2bf(r0.w);
        pk.us[4] = f2bf(r1.x); pk.us[5] = f2bf(r1.y); pk.us[6] = f2bf(r1.z); pk.us[7] = f2bf(r1.w);
        *(bf16x8*)(AsB + arow * 64 + akq * 16) = pk.v;
    }
    __syncthreads();

    // ---- main loop: 32 K-steps, one barrier each ----
    for (int ks = 0; ks < 32; ++ks) {
        const int cur = ks & 1, nxt = cur ^ 1;
        const bool pf = (ks < 31);
        float4 r0, r1;
        if (pf) {
            const int k1 = (ks + 1) * 32;
            // issue next B tile (async -> LDS, drains at this iter's barrier)
#pragma unroll
            for (int i = 0; i < 8; ++i) {
                int chunk = w * 8 + i;
                GLOAD_LDS16(w1tB + (size_t)(chunk * 16 + brow) * 2048 + k1 * 2 + bcolb,
                            BsB + nxt * 32768 + chunk * 1024);
            }
            // issue next A loads (regs; latency hides under compute below)
            const float* ag = ctx + (size_t)(m0 + arow) * DC + k1 + akq * 8;
            r0 = *(const float4*)ag;
            r1 = *(const float4*)(ag + 4);
        }

        // compute current buffer: 12 ds_read_b128, 32 MFMA
        const char* Ab = AsB + cur * 4096 + lr * 64 + lk * 16;
        const char* Bc = BsB + cur * 32768 + (w * 128 + lr) * 64 + lk * 16;
        bf16x8 a[4], bb[8];
#pragma unroll
        for (int mf = 0; mf < 4; ++mf) a[mf] = *(const bf16x8*)(Ab + mf * 1024);
#pragma unroll
        for (int nf = 0; nf < 8; ++nf) bb[nf] = *(const bf16x8*)(Bc + nf * 1024);
#pragma unroll
        for (int nf = 0; nf < 8; ++nf)
#pragma unroll
            for (int mf = 0; mf < 4; ++mf)
                acc[mf][nf] = __builtin_amdgcn_mfma_f32_16x16x32_bf16(a[mf], bb[nf], acc[mf][nf], 0, 0, 0);

        if (pf) {
            // cvt + write next A tile into the other buffer
            union { unsigned short us[8]; bf16x8 v; } pk;
            pk.us[0] = f2bf(r0.x); pk.us[1] = f2bf(r0.y); pk.us[2] = f2bf(r0.z); pk.us[3] = f2bf(r0.w);
            pk.us[4] = f2bf(r1.x); pk.us[5] = f2bf(r1.y); pk.us[6] = f2bf(r1.z); pk.us[7] = f2bf(r1.w);
            *(bf16x8*)(AsB + nxt * 4096 + arow * 64 + akq * 16) = pk.v;
        }
        __syncthreads();
    }

    // ---- epilogue: score[row] = sum_col tanh(acc + qb[col]) * w2[col] ----
    // C/D layout: col = w*128 + nf*16 + lr, row = mf*16 + lk*4 + r.
    const int bq = m0 >> 10;
    const float* qbb = qb + (size_t)bq * Hh;
    float s[4][4] = {{0.f}};
#pragma unroll
    for (int nf = 0; nf < 8; ++nf) {
        int col = w * 128 + nf * 16 + lr;
        float qv = qbb[col];
        float wv = w2[col];
#pragma unroll
        for (int mf = 0; mf < 4; ++mf)
#pragma unroll
            for (int r = 0; r < 4; ++r)
                s[mf][r] += tanhf(acc[mf][nf][r] + qv) * wv;
    }
#pragma unroll
    for (int mf = 0; mf < 4; ++mf)
#pragma unroll
        for (int r = 0; r < 4; ++r) {
            float v = s[mf][r];
#pragma unroll
            for (int off = 8; off; off >>= 1) v += __shfl_xor(v, off, 16);
            if (lr == 0) red[w][mf * 16 + lk * 4 + r] = v;
        }
    __syncthreads();
    if (tid < 64)
        score[m0 + tid] = red[0][tid] + red[1][tid] + red[2][tid] + red[3][tid];
}

// ---------------------------------------------------------------------------
// scan: p = sigmoid(score + b2, masked, + noise); att_l = p_l * prod_{i<l}(1-p_i)
// ---------------------------------------------------------------------------
__global__ __launch_bounds__(64) void scan_kernel(const float* __restrict__ score,
                                                  const int* __restrict__ mask,
                                                  const float* __restrict__ noise,
                                                  const float* __restrict__ b2p,
                                                  float* __restrict__ att) {
    int b = blockIdx.x;
    int lane = threadIdx.x;
    float b2 = b2p[0];
    int base = b * Ll + lane * 16;

    float p[16], q[16];
    float run = 1.f;
#pragma unroll
    for (int j = 0; j < 16; ++j) {
        int l = base + j;
        float s = score[l] + b2;
        if (mask[l] == 0) s = NEG_NUM;
        s += noise[l];
        float pv = 1.f / (1.f + expf(-s));
        p[j] = pv;
        run *= (1.f - pv);
        q[j] = run;
    }
    float incl = run;
#pragma unroll
    for (int off = 1; off < 64; off <<= 1) {
        float v = __shfl_up(incl, off, 64);
        if (lane >= off) incl *= v;
    }
    float excl = __shfl_up(incl, 1, 64);
    if (lane == 0) excl = 1.f;
#pragma unroll
    for (int j = 0; j < 16; ++j) {
        float P = excl * (j == 0 ? 1.f : q[j - 1]);
        att[base + j] = p[j] * P;
    }
}

// ---------------------------------------------------------------------------
// expected_ctx[b,c] = sum_l att[b,l] * ctx[b,l,c]  (fp32 ctx, float4/thread)
// grid (1, 16, 32): 64 L-rows per block, 512 blocks; atomics into zeroed out.
// ---------------------------------------------------------------------------
__global__ __launch_bounds__(256) void ectx_kernel(const float* __restrict__ ctx,
                                                   const float* __restrict__ att,
                                                   float* __restrict__ out) {
    int b = blockIdx.z;
    int c4 = threadIdx.x;                 // c = c4*4
    int l0 = blockIdx.y * 64;
    const float* cb = ctx + ((size_t)b * Ll + l0) * DC + c4 * 4;
    const float* ab = att + (size_t)b * Ll + l0;
    float a0 = 0.f, a1 = 0.f, a2 = 0.f, a3 = 0.f;
#pragma unroll 4
    for (int l = 0; l < 64; ++l) {
        float av = ab[l];
        float4 v = *(const float4*)(cb + (size_t)l * DC);
        a0 += av * v.x; a1 += av * v.y; a2 += av * v.z; a3 += av * v.w;
    }
    float* o = out + (size_t)b * DC + c4 * 4;
    atomicAdd(o + 0, a0); atomicAdd(o + 1, a1);
    atomicAdd(o + 2, a2); atomicAdd(o + 3, a3);
}

// ---------------------------------------------------------------------------
extern "C" void kernel_launch(void* const* d_in, const int* in_sizes, int n_in,
                              void* d_out, int out_size, void* d_ws, size_t ws_size,
                              hipStream_t stream) {
    const float* ctx   = (const float*)d_in[0];
    const float* query = (const float*)d_in[1];
    const int*   mask  = (const int*)d_in[2];
    const float* noise = (const float*)d_in[3];
    const float* W1    = (const float*)d_in[4];
    const float* b1    = (const float*)d_in[5];
    const float* w2    = (const float*)d_in[6];
    const float* b2    = (const float*)d_in[7];

    float* out_ctx = (float*)d_out;                 // [B, DC]
    float* out_att = (float*)d_out + Bb * DC;       // [B, L]

    char* ws = (char*)d_ws;
    float* score = (float*)ws;                                   // 131072 B
    float* qb    = (float*)(ws + 131072);                        //  65536 B
    unsigned short* w1t = (unsigned short*)(ws + 196608);        // 1 MiB
    // total scratch need ~1.25 MB (ws is ~512 MB)

    // w1t transpose-cvt + zero out_ctx + qb (one kernel)
    prep_kernel<<<2432, 256, 0, stream>>>(W1, query, b1, w1t, qb, out_ctx);

    // fused cvt+GEMM+tanh+w2 -> score (no atomics, no zero-init needed)
    gemm_fused<<<(Bb * Ll) / 64, 256, 0, stream>>>(ctx, w1t, qb, w2, score);

    // sigmoid/mask/noise/scan -> att (second output)
    scan_kernel<<<Bb, 64, 0, stream>>>(score, mask, noise, b2, out_att);

    // expected_ctx = att @ ctx (fp32 ctx, L3-resident after gemm)
    ectx_kernel<<<dim3(1, Ll / 64, Bb), 256, 0, stream>>>(ctx, out_att, out_ctx);
}